// Round 10
// baseline (249.719 us; speedup 1.0000x reference)
//
#include <hip/hip_runtime.h>
#include <hip/hip_bf16.h>

// B=2, S=4096, D=768, H=12, d_head=64.
// convert x/W to bf16 (W transposed, Q pre-scaled by 0.125*log2e) ->
// 128^2 m97-style GEMM -> flash attention: 32x32x16 MFMA, in-register P via
// cvt_pk + permlane32_swap (T12), fixed-max softmax, cooperative paired tiles
// (768 uniform 4-wave blocks, XCD-local) -> 128^2 out GEMM.

#define D_MODEL 768
#define SEQ 4096
#define NB 2
#define NHEAD 12
#define LDQK 1536

typedef __attribute__((ext_vector_type(8))) short short8;
typedef __attribute__((ext_vector_type(4))) float floatx4;
typedef __attribute__((ext_vector_type(16))) float floatx16;

#define SM_C 0.18033688011112042f  /* 0.125 * log2(e) */

#if __has_builtin(__builtin_amdgcn_exp2f)
#define EXP2(x) __builtin_amdgcn_exp2f(x)
#else
#define EXP2(x) __expf((x) * 0.6931471805599453f)
#endif

__device__ inline short fb(float f) {             // single f32->bf16 (RNE)
    union { __hip_bfloat16 h; short s; } cv;
    cv.h = __float2bfloat16(f);
    return cv.s;
}
__device__ inline unsigned pk2(float a, float b) { // packed pair -> v_cvt_pk_bf16_f32
    float2 f; f.x = a; f.y = b;
    union { __hip_bfloat162 h; unsigned u; } cv;
    cv.h = __float22bfloat162_rn(f);
    return cv.u;
}
__device__ inline void gload16(const void* g, void* l) {
    __builtin_amdgcn_global_load_lds(
        (const __attribute__((address_space(1))) unsigned int*)g,
        (__attribute__((address_space(3))) unsigned int*)l, 16, 0, 0);
}

// ---------------------------------------------------------------------------
__global__ __launch_bounds__(256) void convert_bf16(const float* __restrict__ src,
                                                    short* __restrict__ dst, size_t n) {
    size_t i = ((size_t)blockIdx.x * 256 + threadIdx.x) * 8;
    if (i >= n) return;
    float4 f0 = *(const float4*)(src + i);
    float4 f1 = *(const float4*)(src + i + 4);
    uint4 u = {pk2(f0.x, f0.y), pk2(f0.z, f0.w), pk2(f1.x, f1.y), pk2(f1.z, f1.w)};
    *(uint4*)(dst + i) = u;
}

// W[K][N] fp32 -> Wt[N][K] bf16, 32x32 tiles. block (32,8).
__global__ __launch_bounds__(256) void transpose_bf16(const float* __restrict__ W,
                                                      short* __restrict__ Wt,
                                                      int K, int N) {
    __shared__ short t[32][33];
    const int n0 = blockIdx.x * 32, k0 = blockIdx.y * 32;
    const int tx = threadIdx.x, ty = threadIdx.y;
#pragma unroll
    for (int j = 0; j < 4; ++j)
        t[ty + j * 8][tx] = fb(W[(size_t)(k0 + ty + j * 8) * N + n0 + tx]);
    __syncthreads();
#pragma unroll
    for (int j = 0; j < 4; ++j)
        Wt[(size_t)(n0 + ty + j * 8) * K + k0 + tx] = t[tx][ty + j * 8];
}

// ---------------------------------------------------------------------------
// QKV GEMM (m97 structure). Q columns (<768) pre-scaled by SM_C for attention.
// ---------------------------------------------------------------------------
__global__ __launch_bounds__(256) void gemm_qkv128(const short* __restrict__ A,
                                                   const short* __restrict__ Bt,
                                                   const float* __restrict__ bias,
                                                   short* __restrict__ qkw,
                                                   short* __restrict__ vtw) {
    const int K = D_MODEL;
    __shared__ short As[128][32];
    __shared__ short Bs[128][32];
    const int tid = threadIdx.x, lane = tid & 63, w = tid >> 6;
    const int wr = w >> 1, wc = w & 1;
    const int lo = lane & 15, hi = lane >> 4;
    const int m0 = blockIdx.y * 128, n0 = blockIdx.x * 128;
    const int lr = lane >> 2, lc = (lane & 3) * 8;

    floatx4 acc[4][4] = {};
    const short* Ag = A  + (size_t)(m0 + w * 16 + lr) * K + lc;
    const short* Bg = Bt + (size_t)(n0 + w * 16 + lr) * K + lc;

    for (int k0 = 0; k0 < K; k0 += 32) {
        __syncthreads();
        gload16(Ag + k0,                  &As[w * 16][0]);
        gload16(Ag + k0 + (size_t)64 * K, &As[64 + w * 16][0]);
        gload16(Bg + k0,                  &Bs[w * 16][0]);
        gload16(Bg + k0 + (size_t)64 * K, &Bs[64 + w * 16][0]);
        __syncthreads();
        short8 a[4], bf[4];
#pragma unroll
        for (int m = 0; m < 4; ++m) a[m] = *(const short8*)&As[wr * 64 + m * 16 + lo][hi * 8];
#pragma unroll
        for (int n = 0; n < 4; ++n) bf[n] = *(const short8*)&Bs[wc * 64 + n * 16 + lo][hi * 8];
#pragma unroll
        for (int m = 0; m < 4; ++m)
#pragma unroll
            for (int n = 0; n < 4; ++n)
                acc[m][n] = __builtin_amdgcn_mfma_f32_16x16x32_bf16(a[m], bf[n], acc[m][n], 0, 0, 0);
    }

#pragma unroll
    for (int m = 0; m < 4; ++m)
#pragma unroll
        for (int n = 0; n < 4; ++n) {
            int col  = n0 + wc * 64 + n * 16 + lo;
            int row0 = m0 + wr * 64 + m * 16 + hi * 4;
            float bv = bias[col];
            if (col < LDQK) {
#pragma unroll
                for (int r = 0; r < 4; ++r) {
                    float v = acc[m][n][r] + bv;
                    if (col < D_MODEL) v *= SM_C;   // pre-scale Q
                    qkw[(size_t)(row0 + r) * LDQK + col] = fb(v);
                }
            } else {
                int vcol = col - LDQK;
                int hh = vcol >> 6, dh = vcol & 63;
                int bb = row0 >> 12, s = row0 & 4095;
                uint2 u = {pk2(acc[m][n][0] + bv, acc[m][n][1] + bv),
                           pk2(acc[m][n][2] + bv, acc[m][n][3] + bv)};
                *(uint2*)&vtw[(((size_t)bb * NHEAD + hh) * 64 + dh) * SEQ + s] = u;
            }
        }
}

// ---------------------------------------------------------------------------
__global__ __launch_bounds__(256) void gemm_out128(const short* __restrict__ A,
                                                   const short* __restrict__ Bt,
                                                   const float* __restrict__ bias,
                                                   float* __restrict__ C) {
    const int K = D_MODEL, N = D_MODEL;
    __shared__ short As[128][32];
    __shared__ short Bs[128][32];
    const int tid = threadIdx.x, lane = tid & 63, w = tid >> 6;
    const int wr = w >> 1, wc = w & 1;
    const int lo = lane & 15, hi = lane >> 4;
    const int m0 = blockIdx.y * 128, n0 = blockIdx.x * 128;
    const int lr = lane >> 2, lc = (lane & 3) * 8;

    floatx4 acc[4][4] = {};
    const short* Ag = A  + (size_t)(m0 + w * 16 + lr) * K + lc;
    const short* Bg = Bt + (size_t)(n0 + w * 16 + lr) * K + lc;

    for (int k0 = 0; k0 < K; k0 += 32) {
        __syncthreads();
        gload16(Ag + k0,                  &As[w * 16][0]);
        gload16(Ag + k0 + (size_t)64 * K, &As[64 + w * 16][0]);
        gload16(Bg + k0,                  &Bs[w * 16][0]);
        gload16(Bg + k0 + (size_t)64 * K, &Bs[64 + w * 16][0]);
        __syncthreads();
        short8 a[4], bf[4];
#pragma unroll
        for (int m = 0; m < 4; ++m) a[m] = *(const short8*)&As[wr * 64 + m * 16 + lo][hi * 8];
#pragma unroll
        for (int n = 0; n < 4; ++n) bf[n] = *(const short8*)&Bs[wc * 64 + n * 16 + lo][hi * 8];
#pragma unroll
        for (int m = 0; m < 4; ++m)
#pragma unroll
            for (int n = 0; n < 4; ++n)
                acc[m][n] = __builtin_amdgcn_mfma_f32_16x16x32_bf16(a[m], bf[n], acc[m][n], 0, 0, 0);
    }

#pragma unroll
    for (int m = 0; m < 4; ++m)
#pragma unroll
        for (int n = 0; n < 4; ++n) {
            int col  = n0 + wc * 64 + n * 16 + lo;
            int row0 = m0 + wr * 64 + m * 16 + hi * 4;
            float bv = bias[col];
#pragma unroll
            for (int r = 0; r < 4; ++r)
                C[(size_t)(row0 + r) * N + col] = acc[m][n][r] + bv;
        }
}

// ---------------------------------------------------------------------------
// Flash attention (causal). 4 waves; pair A (w0,w1) owns tile 63-i, pair B
// (w2,w3) owns tile i then helps tile 63-i's tail keys. 33 uniform iterations;
// 768 uniform blocks, XCD-local. 32x32x16 MFMA; P in-register via cvt_pk +
// v_permlane32_swap; fixed-max softmax (Q pre-scaled); fp32 combine via LDS.
// ---------------------------------------------------------------------------
__global__ __launch_bounds__(256, 4) void attn_k(const short* __restrict__ qk,
                                                 const short* __restrict__ vt,
                                                 short* __restrict__ y) {
    const int L = blockIdx.x;
    const int xcd = L & 7, slot = L >> 3;
    const int ghead = slot >> 5, ip = slot & 31;
    const int g = ghead * 8 + xcd;
    const int b = g / NHEAD, h = g % NHEAD;

    const int tid = threadIdx.x, lane = tid & 63, w = tid >> 6;
    const int q32 = lane & 31, hh = lane >> 5;
    const int pairB = w >> 1;            // 0: waves 0,1   1: waves 2,3
    const int wrow = (w & 1) * 32;

    __shared__ alignas(16) short KVs[2][2][64 * 64];  // [pair][K,V]: row*64 + (blk8^(row&7))*8
    __shared__ float Lcmb[128];

    const short* qbase = qk + (size_t)b * SEQ * LDQK;
    const short* kbase = qbase + D_MODEL;
    const short* vbase = vt + ((size_t)b * NHEAD + h) * 64 * SEQ;

    short* Kb = KVs[pairB][0];
    short* Vb = KVs[pairB][1];

    // staging: 128 threads per pair; thread: row = lt>>1, 32 elems at half lt&1
    const int lt = tid & 127;
    const int srow = lt >> 1, shalf = lt & 1;
    int cof[4];
#pragma unroll
    for (int jj = 0; jj < 4; ++jj)
        cof[jj] = srow * 64 + ((shalf * 4 + jj) ^ (srow & 7)) * 8;

    const int qt_hi = 63 - ip, qt_lo = ip;
    int tq0 = (pairB ? qt_lo : qt_hi) * 64;

    short8 qf[4];
    {
        const short* qr = qbase + (size_t)(tq0 + wrow + q32) * LDQK + h * 64 + hh * 8;
        qf[0] = *(const short8*)(qr);
        qf[1] = *(const short8*)(qr + 16);
        qf[2] = *(const short8*)(qr + 32);
        qf[3] = *(const short8*)(qr + 48);
    }

    floatx16 O0 = {}, O1 = {};
    float lsum = 0.0f;

    short8 kpre[4], vpre[4];
    {
        const short* kg = kbase + (size_t)srow * LDQK + h * 64 + shalf * 32;
        const short* vg = vbase + (size_t)srow * SEQ + shalf * 32;
#pragma unroll
        for (int jj = 0; jj < 4; ++jj) {
            kpre[jj] = *(const short8*)(kg + jj * 8);
            vpre[jj] = *(const short8*)(vg + jj * 8);
        }
    }
    int curblk = 0;

    auto store_out = [&](float ltot) {
        float inv = 1.0f / ltot;
#pragma unroll
        for (int r = 0; r < 16; ++r) {
            int qrow = (r & 3) + 8 * (r >> 2) + 4 * hh;
            float iv = __shfl(inv, qrow, 64);
            short* d = y + ((size_t)b * SEQ + tq0 + wrow + qrow) * D_MODEL + h * 64;
            d[q32]      = fb(O0[r] * iv);
            d[32 + q32] = fb(O1[r] * iv);
        }
    };

    for (int j = 0; j <= 32; ++j) {
        __syncthreads();
        if (curblk >= 0) {
#pragma unroll
            for (int jj = 0; jj < 4; ++jj) {
                *(short8*)&Kb[cof[jj]] = kpre[jj];
                *(short8*)&Vb[cof[jj]] = vpre[jj];
            }
        }
        __syncthreads();

        // prefetch next block into regs
        int nxt;
        {
            int jn = j + 1;
            if (!pairB) nxt = (jn <= 32) ? jn : -1;
            else        nxt = (jn <= ip) ? jn : (jn <= 31 ? 32 + (jn - ip) : -1);
        }
        if (nxt >= 0) {
            const short* kg = kbase + (size_t)(nxt * 64 + srow) * LDQK + h * 64 + shalf * 32;
            const short* vg = vbase + (size_t)srow * SEQ + nxt * 64 + shalf * 32;
#pragma unroll
            for (int jj = 0; jj < 4; ++jj) {
                kpre[jj] = *(const short8*)(kg + jj * 8);
                vpre[jj] = *(const short8*)(vg + jj * 8);
            }
        }

        // pair B: finalize T_lo and retarget to T_hi tail
        if (pairB && j == ip + 1) {
            float ltot = lsum + __shfl_xor(lsum, 32, 64);
            store_out(ltot);
#pragma unroll
            for (int r = 0; r < 16; ++r) { O0[r] = 0.0f; O1[r] = 0.0f; }
            lsum = 0.0f;
            tq0 = qt_hi * 64;
            const short* qr = qbase + (size_t)(tq0 + wrow + q32) * LDQK + h * 64 + hh * 8;
            qf[0] = *(const short8*)(qr);
            qf[1] = *(const short8*)(qr + 16);
            qf[2] = *(const short8*)(qr + 32);
            qf[3] = *(const short8*)(qr + 48);
        }

        if (curblk >= 0) {
            const int myqt = (pairB && j <= ip) ? qt_lo : qt_hi;
            const bool diag = (curblk == myqt);

#pragma unroll
            for (int kb2 = 0; kb2 < 2; ++kb2) {
                floatx16 S = {};
                __builtin_amdgcn_s_setprio(1);
#pragma unroll
                for (int kc = 0; kc < 4; ++kc) {
                    short8 kf = *(const short8*)&Kb[(kb2 * 32 + q32) * 64 + ((kc * 2 + hh) ^ (q32 & 7)) * 8];
                    S = __builtin_amdgcn_mfma_f32_32x32x16_bf16(kf, qf[kc], S, 0, 0, 0);
                }
                __builtin_amdgcn_s_setprio(0);

                if (diag) {
                    int qg = tq0 + wrow + q32;
                    int kb_base = curblk * 64 + kb2 * 32 + 4 * hh;
#pragma unroll
                    for (int r = 0; r < 16; ++r) {
                        int kgl = kb_base + (r & 3) + 8 * (r >> 2);
                        if (kgl > qg) S[r] = -1e30f;
                    }
                }

                unsigned wA[4], wB[4];
#pragma unroll
                for (int g4 = 0; g4 < 4; ++g4) {
                    float p0 = EXP2(S[4 * g4 + 0]), p1 = EXP2(S[4 * g4 + 1]);
                    float p2 = EXP2(S[4 * g4 + 2]), p3 = EXP2(S[4 * g4 + 3]);
                    lsum += (p0 + p1) + (p2 + p3);
                    wA[g4] = pk2(p0, p1);
                    wB[g4] = pk2(p2, p3);
                }
#pragma unroll
                for (int c16 = 0; c16 < 2; ++c16) {
                    unsigned xa = wA[2 * c16], ya = wA[2 * c16 + 1];
                    unsigned xb = wB[2 * c16], yb = wB[2 * c16 + 1];
                    asm("v_permlane32_swap_b32 %0, %1" : "+v"(xa), "+v"(ya));
                    asm("v_permlane32_swap_b32 %0, %1" : "+v"(xb), "+v"(yb));
                    union { unsigned u[4]; short8 s; } pa;
                    pa.u[0] = xa; pa.u[1] = xb; pa.u[2] = ya; pa.u[3] = yb;
                    const int kc = kb2 * 2 + c16;
                    short8 vf0 = *(const short8*)&Vb[q32 * 64 + ((kc * 2 + hh) ^ (q32 & 7)) * 8];
                    short8 vf1 = *(const short8*)&Vb[(32 + q32) * 64 + ((kc * 2 + hh) ^ (q32 & 7)) * 8];
                    __builtin_amdgcn_s_setprio(1);
                    O0 = __builtin_amdgcn_mfma_f32_32x32x16_bf16(pa.s, vf0, O0, 0, 0, 0);
                    O1 = __builtin_amdgcn_mfma_f32_32x32x16_bf16(pa.s, vf1, O1, 0, 0, 0);
                    __builtin_amdgcn_s_setprio(0);
                }
            }
        }
        curblk = nxt;
    }

    // combine: B writes fp32 partials over its own (now-dead) buffers; A adds.
    if (pairB) {
        float* cO = (float*)&KVs[1][0][0];   // 16 KB: [32 regs][128 lanes]
        const int lane2 = (w & 1) * 64 + lane;
#pragma unroll
        for (int r = 0; r < 16; ++r) {
            cO[r * 128 + lane2]        = O0[r];
            cO[(16 + r) * 128 + lane2] = O1[r];
        }
        Lcmb[lane2] = lsum;
    }
    __syncthreads();
    if (!pairB) {
        const float* cO = (const float*)&KVs[1][0][0];
        const int lane2 = (w & 1) * 64 + lane;
#pragma unroll
        for (int r = 0; r < 16; ++r) {
            O0[r] += cO[r * 128 + lane2];
            O1[r] += cO[(16 + r) * 128 + lane2];
        }
        lsum += Lcmb[lane2];
        float ltot = lsum + __shfl_xor(lsum, 32, 64);
        store_out(ltot);
    }
}

extern "C" void kernel_launch(void* const* d_in, const int* in_sizes, int n_in,
                              void* d_out, int out_size, void* d_ws, size_t ws_size,
                              hipStream_t stream) {
    (void)in_sizes; (void)n_in; (void)out_size; (void)ws_size;
    const float* x     = (const float*)d_in[0];
    const float* W_in  = (const float*)d_in[1];
    const float* b_in  = (const float*)d_in[2];
    const float* W_out = (const float*)d_in[3];
    const float* b_out = (const float*)d_in[4];
    float* out = (float*)d_out;

    const int M = NB * SEQ;  // 8192
    char* p = (char*)d_ws;
    short* xbf   = (short*)p; p += (size_t)M * D_MODEL * 2;
    short* wtin  = (short*)p; p += (size_t)3 * D_MODEL * D_MODEL * 2;
    short* wtout = (short*)p; p += (size_t)D_MODEL * D_MODEL * 2;
    short* qkw   = (short*)p; p += (size_t)M * LDQK * 2;
    short* vtw   = (short*)p; p += (size_t)NB * NHEAD * 64 * SEQ * 2;
    short* yw    = (short*)p;

    convert_bf16<<<dim3((unsigned)((size_t)M * D_MODEL / 8 / 256)), 256, 0, stream>>>(
        x, xbf, (size_t)M * D_MODEL);
    transpose_bf16<<<dim3(3 * D_MODEL / 32, D_MODEL / 32), dim3(32, 8), 0, stream>>>(
        W_in, wtin, D_MODEL, 3 * D_MODEL);
    transpose_bf16<<<dim3(D_MODEL / 32, D_MODEL / 32), dim3(32, 8), 0, stream>>>(
        W_out, wtout, D_MODEL, D_MODEL);
    gemm_qkv128<<<dim3(3 * D_MODEL / 128, M / 128), 256, 0, stream>>>(
        xbf, wtin, b_in, qkw, vtw);
    attn_k<<<dim3(NB * NHEAD * (SEQ / 128)), 256, 0, stream>>>(qkw, vtw, yw);
    gemm_out128<<<dim3(D_MODEL / 128, M / 128), 256, 0, stream>>>(yw, wtout, b_out, out);
}

// Round 11
// 176.830 us; speedup vs baseline: 1.4122x; 1.4122x over previous
//
#include <hip/hip_runtime.h>
#include <hip/hip_bf16.h>

// B=2, S=4096, D=768, H=12, d_head=64.
// convert x/W to bf16 (W transposed, Q pre-scaled by 0.125*log2e) ->
// 128^2 m97-style GEMM -> flash attention: 32x32x16 MFMA, in-register P via
// cvt_pk + permlane32_swap (T12), fixed-max softmax, cooperative paired tiles
// (768 uniform 4-wave blocks, XCD-local) -> 128^2 out GEMM.
// R11 = R10 with launch_bounds(256,3): R10 spilled (VGPR capped 128 by ",4",
// WRITE_SIZE 206MB of scratch). 3 waves/SIMD is all we need (768 blocks).

#define D_MODEL 768
#define SEQ 4096
#define NB 2
#define NHEAD 12
#define LDQK 1536

typedef __attribute__((ext_vector_type(8))) short short8;
typedef __attribute__((ext_vector_type(4))) float floatx4;
typedef __attribute__((ext_vector_type(16))) float floatx16;

#define SM_C 0.18033688011112042f  /* 0.125 * log2(e) */

#if __has_builtin(__builtin_amdgcn_exp2f)
#define EXP2(x) __builtin_amdgcn_exp2f(x)
#else
#define EXP2(x) __expf((x) * 0.6931471805599453f)
#endif

__device__ inline short fb(float f) {             // single f32->bf16 (RNE)
    union { __hip_bfloat16 h; short s; } cv;
    cv.h = __float2bfloat16(f);
    return cv.s;
}
__device__ inline unsigned pk2(float a, float b) { // packed pair -> v_cvt_pk_bf16_f32
    float2 f; f.x = a; f.y = b;
    union { __hip_bfloat162 h; unsigned u; } cv;
    cv.h = __float22bfloat162_rn(f);
    return cv.u;
}
__device__ inline void gload16(const void* g, void* l) {
    __builtin_amdgcn_global_load_lds(
        (const __attribute__((address_space(1))) unsigned int*)g,
        (__attribute__((address_space(3))) unsigned int*)l, 16, 0, 0);
}

// ---------------------------------------------------------------------------
__global__ __launch_bounds__(256) void convert_bf16(const float* __restrict__ src,
                                                    short* __restrict__ dst, size_t n) {
    size_t i = ((size_t)blockIdx.x * 256 + threadIdx.x) * 8;
    if (i >= n) return;
    float4 f0 = *(const float4*)(src + i);
    float4 f1 = *(const float4*)(src + i + 4);
    uint4 u = {pk2(f0.x, f0.y), pk2(f0.z, f0.w), pk2(f1.x, f1.y), pk2(f1.z, f1.w)};
    *(uint4*)(dst + i) = u;
}

// W[K][N] fp32 -> Wt[N][K] bf16, 32x32 tiles. block (32,8).
__global__ __launch_bounds__(256) void transpose_bf16(const float* __restrict__ W,
                                                      short* __restrict__ Wt,
                                                      int K, int N) {
    __shared__ short t[32][33];
    const int n0 = blockIdx.x * 32, k0 = blockIdx.y * 32;
    const int tx = threadIdx.x, ty = threadIdx.y;
#pragma unroll
    for (int j = 0; j < 4; ++j)
        t[ty + j * 8][tx] = fb(W[(size_t)(k0 + ty + j * 8) * N + n0 + tx]);
    __syncthreads();
#pragma unroll
    for (int j = 0; j < 4; ++j)
        Wt[(size_t)(n0 + ty + j * 8) * K + k0 + tx] = t[tx][ty + j * 8];
}

// ---------------------------------------------------------------------------
// QKV GEMM (m97 structure). Q columns (<768) pre-scaled by SM_C for attention.
// ---------------------------------------------------------------------------
__global__ __launch_bounds__(256) void gemm_qkv128(const short* __restrict__ A,
                                                   const short* __restrict__ Bt,
                                                   const float* __restrict__ bias,
                                                   short* __restrict__ qkw,
                                                   short* __restrict__ vtw) {
    const int K = D_MODEL;
    __shared__ short As[128][32];
    __shared__ short Bs[128][32];
    const int tid = threadIdx.x, lane = tid & 63, w = tid >> 6;
    const int wr = w >> 1, wc = w & 1;
    const int lo = lane & 15, hi = lane >> 4;
    const int m0 = blockIdx.y * 128, n0 = blockIdx.x * 128;
    const int lr = lane >> 2, lc = (lane & 3) * 8;

    floatx4 acc[4][4] = {};
    const short* Ag = A  + (size_t)(m0 + w * 16 + lr) * K + lc;
    const short* Bg = Bt + (size_t)(n0 + w * 16 + lr) * K + lc;

    for (int k0 = 0; k0 < K; k0 += 32) {
        __syncthreads();
        gload16(Ag + k0,                  &As[w * 16][0]);
        gload16(Ag + k0 + (size_t)64 * K, &As[64 + w * 16][0]);
        gload16(Bg + k0,                  &Bs[w * 16][0]);
        gload16(Bg + k0 + (size_t)64 * K, &Bs[64 + w * 16][0]);
        __syncthreads();
        short8 a[4], bf[4];
#pragma unroll
        for (int m = 0; m < 4; ++m) a[m] = *(const short8*)&As[wr * 64 + m * 16 + lo][hi * 8];
#pragma unroll
        for (int n = 0; n < 4; ++n) bf[n] = *(const short8*)&Bs[wc * 64 + n * 16 + lo][hi * 8];
#pragma unroll
        for (int m = 0; m < 4; ++m)
#pragma unroll
            for (int n = 0; n < 4; ++n)
                acc[m][n] = __builtin_amdgcn_mfma_f32_16x16x32_bf16(a[m], bf[n], acc[m][n], 0, 0, 0);
    }

#pragma unroll
    for (int m = 0; m < 4; ++m)
#pragma unroll
        for (int n = 0; n < 4; ++n) {
            int col  = n0 + wc * 64 + n * 16 + lo;
            int row0 = m0 + wr * 64 + m * 16 + hi * 4;
            float bv = bias[col];
            if (col < LDQK) {
#pragma unroll
                for (int r = 0; r < 4; ++r) {
                    float v = acc[m][n][r] + bv;
                    if (col < D_MODEL) v *= SM_C;   // pre-scale Q
                    qkw[(size_t)(row0 + r) * LDQK + col] = fb(v);
                }
            } else {
                int vcol = col - LDQK;
                int hh = vcol >> 6, dh = vcol & 63;
                int bb = row0 >> 12, s = row0 & 4095;
                uint2 u = {pk2(acc[m][n][0] + bv, acc[m][n][1] + bv),
                           pk2(acc[m][n][2] + bv, acc[m][n][3] + bv)};
                *(uint2*)&vtw[(((size_t)bb * NHEAD + hh) * 64 + dh) * SEQ + s] = u;
            }
        }
}

// ---------------------------------------------------------------------------
__global__ __launch_bounds__(256) void gemm_out128(const short* __restrict__ A,
                                                   const short* __restrict__ Bt,
                                                   const float* __restrict__ bias,
                                                   float* __restrict__ C) {
    const int K = D_MODEL, N = D_MODEL;
    __shared__ short As[128][32];
    __shared__ short Bs[128][32];
    const int tid = threadIdx.x, lane = tid & 63, w = tid >> 6;
    const int wr = w >> 1, wc = w & 1;
    const int lo = lane & 15, hi = lane >> 4;
    const int m0 = blockIdx.y * 128, n0 = blockIdx.x * 128;
    const int lr = lane >> 2, lc = (lane & 3) * 8;

    floatx4 acc[4][4] = {};
    const short* Ag = A  + (size_t)(m0 + w * 16 + lr) * K + lc;
    const short* Bg = Bt + (size_t)(n0 + w * 16 + lr) * K + lc;

    for (int k0 = 0; k0 < K; k0 += 32) {
        __syncthreads();
        gload16(Ag + k0,                  &As[w * 16][0]);
        gload16(Ag + k0 + (size_t)64 * K, &As[64 + w * 16][0]);
        gload16(Bg + k0,                  &Bs[w * 16][0]);
        gload16(Bg + k0 + (size_t)64 * K, &Bs[64 + w * 16][0]);
        __syncthreads();
        short8 a[4], bf[4];
#pragma unroll
        for (int m = 0; m < 4; ++m) a[m] = *(const short8*)&As[wr * 64 + m * 16 + lo][hi * 8];
#pragma unroll
        for (int n = 0; n < 4; ++n) bf[n] = *(const short8*)&Bs[wc * 64 + n * 16 + lo][hi * 8];
#pragma unroll
        for (int m = 0; m < 4; ++m)
#pragma unroll
            for (int n = 0; n < 4; ++n)
                acc[m][n] = __builtin_amdgcn_mfma_f32_16x16x32_bf16(a[m], bf[n], acc[m][n], 0, 0, 0);
    }

#pragma unroll
    for (int m = 0; m < 4; ++m)
#pragma unroll
        for (int n = 0; n < 4; ++n) {
            int col  = n0 + wc * 64 + n * 16 + lo;
            int row0 = m0 + wr * 64 + m * 16 + hi * 4;
            float bv = bias[col];
#pragma unroll
            for (int r = 0; r < 4; ++r)
                C[(size_t)(row0 + r) * N + col] = acc[m][n][r] + bv;
        }
}

// ---------------------------------------------------------------------------
// Flash attention (causal). 4 waves; pair A (w0,w1) owns tile 63-i, pair B
// (w2,w3) owns tile i then helps tile 63-i's tail keys. 33 uniform iterations;
// 768 uniform blocks, XCD-local. 32x32x16 MFMA; P in-register via cvt_pk +
// v_permlane32_swap; fixed-max softmax (Q pre-scaled); fp32 combine via LDS.
// ---------------------------------------------------------------------------
__global__ __launch_bounds__(256, 3) void attn_k(const short* __restrict__ qk,
                                                 const short* __restrict__ vt,
                                                 short* __restrict__ y) {
    const int L = blockIdx.x;
    const int xcd = L & 7, slot = L >> 3;
    const int ghead = slot >> 5, ip = slot & 31;
    const int g = ghead * 8 + xcd;
    const int b = g / NHEAD, h = g % NHEAD;

    const int tid = threadIdx.x, lane = tid & 63, w = tid >> 6;
    const int q32 = lane & 31, hh = lane >> 5;
    const int pairB = w >> 1;            // 0: waves 0,1   1: waves 2,3
    const int wrow = (w & 1) * 32;

    __shared__ alignas(16) short KVs[2][2][64 * 64];  // [pair][K,V]: row*64 + (blk8^(row&7))*8
    __shared__ float Lcmb[128];

    const short* qbase = qk + (size_t)b * SEQ * LDQK;
    const short* kbase = qbase + D_MODEL;
    const short* vbase = vt + ((size_t)b * NHEAD + h) * 64 * SEQ;

    short* Kb = KVs[pairB][0];
    short* Vb = KVs[pairB][1];

    // staging: 128 threads per pair; thread: row = lt>>1, 32 elems at half lt&1
    const int lt = tid & 127;
    const int srow = lt >> 1, shalf = lt & 1;
    int cof[4];
#pragma unroll
    for (int jj = 0; jj < 4; ++jj)
        cof[jj] = srow * 64 + ((shalf * 4 + jj) ^ (srow & 7)) * 8;

    const int qt_hi = 63 - ip, qt_lo = ip;
    int tq0 = (pairB ? qt_lo : qt_hi) * 64;

    short8 qf[4];
    {
        const short* qr = qbase + (size_t)(tq0 + wrow + q32) * LDQK + h * 64 + hh * 8;
        qf[0] = *(const short8*)(qr);
        qf[1] = *(const short8*)(qr + 16);
        qf[2] = *(const short8*)(qr + 32);
        qf[3] = *(const short8*)(qr + 48);
    }

    floatx16 O0 = {}, O1 = {};
    float lsum = 0.0f;

    short8 kpre[4], vpre[4];
    {
        const short* kg = kbase + (size_t)srow * LDQK + h * 64 + shalf * 32;
        const short* vg = vbase + (size_t)srow * SEQ + shalf * 32;
#pragma unroll
        for (int jj = 0; jj < 4; ++jj) {
            kpre[jj] = *(const short8*)(kg + jj * 8);
            vpre[jj] = *(const short8*)(vg + jj * 8);
        }
    }
    int curblk = 0;

    auto store_out = [&](float ltot) {
        float inv = 1.0f / ltot;
#pragma unroll
        for (int r = 0; r < 16; ++r) {
            int qrow = (r & 3) + 8 * (r >> 2) + 4 * hh;
            float iv = __shfl(inv, qrow, 64);
            short* d = y + ((size_t)b * SEQ + tq0 + wrow + qrow) * D_MODEL + h * 64;
            d[q32]      = fb(O0[r] * iv);
            d[32 + q32] = fb(O1[r] * iv);
        }
    };

    for (int j = 0; j <= 32; ++j) {
        __syncthreads();
        if (curblk >= 0) {
#pragma unroll
            for (int jj = 0; jj < 4; ++jj) {
                *(short8*)&Kb[cof[jj]] = kpre[jj];
                *(short8*)&Vb[cof[jj]] = vpre[jj];
            }
        }
        __syncthreads();

        // prefetch next block into regs
        int nxt;
        {
            int jn = j + 1;
            if (!pairB) nxt = (jn <= 32) ? jn : -1;
            else        nxt = (jn <= ip) ? jn : (jn <= 31 ? 32 + (jn - ip) : -1);
        }
        if (nxt >= 0) {
            const short* kg = kbase + (size_t)(nxt * 64 + srow) * LDQK + h * 64 + shalf * 32;
            const short* vg = vbase + (size_t)srow * SEQ + nxt * 64 + shalf * 32;
#pragma unroll
            for (int jj = 0; jj < 4; ++jj) {
                kpre[jj] = *(const short8*)(kg + jj * 8);
                vpre[jj] = *(const short8*)(vg + jj * 8);
            }
        }

        // pair B: finalize T_lo and retarget to T_hi tail
        if (pairB && j == ip + 1) {
            float ltot = lsum + __shfl_xor(lsum, 32, 64);
            store_out(ltot);
#pragma unroll
            for (int r = 0; r < 16; ++r) { O0[r] = 0.0f; O1[r] = 0.0f; }
            lsum = 0.0f;
            tq0 = qt_hi * 64;
            const short* qr = qbase + (size_t)(tq0 + wrow + q32) * LDQK + h * 64 + hh * 8;
            qf[0] = *(const short8*)(qr);
            qf[1] = *(const short8*)(qr + 16);
            qf[2] = *(const short8*)(qr + 32);
            qf[3] = *(const short8*)(qr + 48);
        }

        if (curblk >= 0) {
            const int myqt = (pairB && j <= ip) ? qt_lo : qt_hi;
            const bool diag = (curblk == myqt);

#pragma unroll
            for (int kb2 = 0; kb2 < 2; ++kb2) {
                floatx16 S = {};
                __builtin_amdgcn_s_setprio(1);
#pragma unroll
                for (int kc = 0; kc < 4; ++kc) {
                    short8 kf = *(const short8*)&Kb[(kb2 * 32 + q32) * 64 + ((kc * 2 + hh) ^ (q32 & 7)) * 8];
                    S = __builtin_amdgcn_mfma_f32_32x32x16_bf16(kf, qf[kc], S, 0, 0, 0);
                }
                __builtin_amdgcn_s_setprio(0);

                if (diag) {
                    int qg = tq0 + wrow + q32;
                    int kb_base = curblk * 64 + kb2 * 32 + 4 * hh;
#pragma unroll
                    for (int r = 0; r < 16; ++r) {
                        int kgl = kb_base + (r & 3) + 8 * (r >> 2);
                        if (kgl > qg) S[r] = -1e30f;
                    }
                }

                unsigned wA[4], wB[4];
#pragma unroll
                for (int g4 = 0; g4 < 4; ++g4) {
                    float p0 = EXP2(S[4 * g4 + 0]), p1 = EXP2(S[4 * g4 + 1]);
                    float p2 = EXP2(S[4 * g4 + 2]), p3 = EXP2(S[4 * g4 + 3]);
                    lsum += (p0 + p1) + (p2 + p3);
                    wA[g4] = pk2(p0, p1);
                    wB[g4] = pk2(p2, p3);
                }
#pragma unroll
                for (int c16 = 0; c16 < 2; ++c16) {
                    unsigned xa = wA[2 * c16], ya = wA[2 * c16 + 1];
                    unsigned xb = wB[2 * c16], yb = wB[2 * c16 + 1];
                    asm("v_permlane32_swap_b32 %0, %1" : "+v"(xa), "+v"(ya));
                    asm("v_permlane32_swap_b32 %0, %1" : "+v"(xb), "+v"(yb));
                    union { unsigned u[4]; short8 s; } pa;
                    pa.u[0] = xa; pa.u[1] = xb; pa.u[2] = ya; pa.u[3] = yb;
                    const int kc = kb2 * 2 + c16;
                    short8 vf0 = *(const short8*)&Vb[q32 * 64 + ((kc * 2 + hh) ^ (q32 & 7)) * 8];
                    short8 vf1 = *(const short8*)&Vb[(32 + q32) * 64 + ((kc * 2 + hh) ^ (q32 & 7)) * 8];
                    __builtin_amdgcn_s_setprio(1);
                    O0 = __builtin_amdgcn_mfma_f32_32x32x16_bf16(pa.s, vf0, O0, 0, 0, 0);
                    O1 = __builtin_amdgcn_mfma_f32_32x32x16_bf16(pa.s, vf1, O1, 0, 0, 0);
                    __builtin_amdgcn_s_setprio(0);
                }
            }
        }
        curblk = nxt;
    }

    // combine: B writes fp32 partials over its own (now-dead) buffers; A adds.
    if (pairB) {
        float* cO = (float*)&KVs[1][0][0];   // 16 KB: [32 regs][128 lanes]
        const int lane2 = (w & 1) * 64 + lane;
#pragma unroll
        for (int r = 0; r < 16; ++r) {
            cO[r * 128 + lane2]        = O0[r];
            cO[(16 + r) * 128 + lane2] = O1[r];
        }
        Lcmb[lane2] = lsum;
    }
    __syncthreads();
    if (!pairB) {
        const float* cO = (const float*)&KVs[1][0][0];
        const int lane2 = (w & 1) * 64 + lane;
#pragma unroll
        for (int r = 0; r < 16; ++r) {
            O0[r] += cO[r * 128 + lane2];
            O1[r] += cO[(16 + r) * 128 + lane2];
        }
        lsum += Lcmb[lane2];
        float ltot = lsum + __shfl_xor(lsum, 32, 64);
        store_out(ltot);
    }
}

extern "C" void kernel_launch(void* const* d_in, const int* in_sizes, int n_in,
                              void* d_out, int out_size, void* d_ws, size_t ws_size,
                              hipStream_t stream) {
    (void)in_sizes; (void)n_in; (void)out_size; (void)ws_size;
    const float* x     = (const float*)d_in[0];
    const float* W_in  = (const float*)d_in[1];
    const float* b_in  = (const float*)d_in[2];
    const float* W_out = (const float*)d_in[3];
    const float* b_out = (const float*)d_in[4];
    float* out = (float*)d_out;

    const int M = NB * SEQ;  // 8192
    char* p = (char*)d_ws;
    short* xbf   = (short*)p; p += (size_t)M * D_MODEL * 2;
    short* wtin  = (short*)p; p += (size_t)3 * D_MODEL * D_MODEL * 2;
    short* wtout = (short*)p; p += (size_t)D_MODEL * D_MODEL * 2;
    short* qkw   = (short*)p; p += (size_t)M * LDQK * 2;
    short* vtw   = (short*)p; p += (size_t)NB * NHEAD * 64 * SEQ * 2;
    short* yw    = (short*)p;

    convert_bf16<<<dim3((unsigned)((size_t)M * D_MODEL / 8 / 256)), 256, 0, stream>>>(
        x, xbf, (size_t)M * D_MODEL);
    transpose_bf16<<<dim3(3 * D_MODEL / 32, D_MODEL / 32), dim3(32, 8), 0, stream>>>(
        W_in, wtin, D_MODEL, 3 * D_MODEL);
    transpose_bf16<<<dim3(D_MODEL / 32, D_MODEL / 32), dim3(32, 8), 0, stream>>>(
        W_out, wtout, D_MODEL, D_MODEL);
    gemm_qkv128<<<dim3(3 * D_MODEL / 128, M / 128), 256, 0, stream>>>(
        xbf, wtin, b_in, qkw, vtw);
    attn_k<<<dim3(NB * NHEAD * (SEQ / 128)), 256, 0, stream>>>(qkw, vtw, yw);
    gemm_out128<<<dim3(D_MODEL / 128, M / 128), 256, 0, stream>>>(yw, wtout, b_out, out);
}

// Round 12
// 171.165 us; speedup vs baseline: 1.4589x; 1.0331x over previous
//
#include <hip/hip_runtime.h>
#include <hip/hip_bf16.h>

// B=2, S=4096, D=768, H=12, d_head=64.
// convert x/W to bf16 (W transposed, Q pre-scaled) -> 128^2 m97 GEMM whose
// epilogue writes K/V in PRE-SWIZZLED 8KB LDS-image blocks -> flash attention
// (32x32x16 MFMA, in-reg P via cvt_pk+permlane32_swap, fixed-max softmax,
// cooperative paired tiles, global_load_lds staging) -> 128^2 out GEMM.

#define D_MODEL 768
#define SEQ 4096
#define NB 2
#define NHEAD 12

typedef __attribute__((ext_vector_type(8))) short short8;
typedef __attribute__((ext_vector_type(4))) float floatx4;
typedef __attribute__((ext_vector_type(16))) float floatx16;

#define SM_C 0.18033688011112042f  /* 0.125 * log2(e) */

#if __has_builtin(__builtin_amdgcn_exp2f)
#define EXP2(x) __builtin_amdgcn_exp2f(x)
#else
#define EXP2(x) __expf((x) * 0.6931471805599453f)
#endif

__device__ inline short fb(float f) {
    union { __hip_bfloat16 h; short s; } cv;
    cv.h = __float2bfloat16(f);
    return cv.s;
}
__device__ inline unsigned pk2(float a, float b) {
    float2 f; f.x = a; f.y = b;
    union { __hip_bfloat162 h; unsigned u; } cv;
    cv.h = __float22bfloat162_rn(f);
    return cv.u;
}
__device__ inline void gload16(const void* g, void* l) {
    __builtin_amdgcn_global_load_lds(
        (const __attribute__((address_space(1))) unsigned int*)g,
        (__attribute__((address_space(3))) unsigned int*)l, 16, 0, 0);
}

// ---------------------------------------------------------------------------
__global__ __launch_bounds__(256) void convert_bf16(const float* __restrict__ src,
                                                    short* __restrict__ dst, size_t n) {
    size_t i = ((size_t)blockIdx.x * 256 + threadIdx.x) * 8;
    if (i >= n) return;
    float4 f0 = *(const float4*)(src + i);
    float4 f1 = *(const float4*)(src + i + 4);
    uint4 u = {pk2(f0.x, f0.y), pk2(f0.z, f0.w), pk2(f1.x, f1.y), pk2(f1.z, f1.w)};
    *(uint4*)(dst + i) = u;
}

// W[K][N] fp32 -> Wt[N][K] bf16, 32x32 tiles. block (32,8).
__global__ __launch_bounds__(256) void transpose_bf16(const float* __restrict__ W,
                                                      short* __restrict__ Wt,
                                                      int K, int N) {
    __shared__ short t[32][33];
    const int n0 = blockIdx.x * 32, k0 = blockIdx.y * 32;
    const int tx = threadIdx.x, ty = threadIdx.y;
#pragma unroll
    for (int j = 0; j < 4; ++j)
        t[ty + j * 8][tx] = fb(W[(size_t)(k0 + ty + j * 8) * N + n0 + tx]);
    __syncthreads();
#pragma unroll
    for (int j = 0; j < 4; ++j)
        Wt[(size_t)(n0 + ty + j * 8) * K + k0 + tx] = t[tx][ty + j * 8];
}

// ---------------------------------------------------------------------------
// QKV GEMM (m97 structure). Epilogue routes:
//   col <  768 : Q -> qw[b*4096+s][768], pre-scaled by SM_C
//   col < 1536 : K -> kblk image: blk 8KB = [key][ (dblk^(key&7)) ][8]
//   else       : V -> vblk image: blk 8KB = [dim][ (kblk8^(dim&7)) ][8]
// ---------------------------------------------------------------------------
__global__ __launch_bounds__(256) void gemm_qkv128(const short* __restrict__ A,
                                                   const short* __restrict__ Bt,
                                                   const float* __restrict__ bias,
                                                   short* __restrict__ qw,
                                                   short* __restrict__ kblk,
                                                   short* __restrict__ vblk) {
    const int K = D_MODEL;
    __shared__ short As[128][32];
    __shared__ short Bs[128][32];
    const int tid = threadIdx.x, lane = tid & 63, w = tid >> 6;
    const int wr = w >> 1, wc = w & 1;
    const int lo = lane & 15, hi = lane >> 4;
    const int m0 = blockIdx.y * 128, n0 = blockIdx.x * 128;
    const int lr = lane >> 2, lc = (lane & 3) * 8;

    floatx4 acc[4][4] = {};
    const short* Ag = A  + (size_t)(m0 + w * 16 + lr) * K + lc;
    const short* Bg = Bt + (size_t)(n0 + w * 16 + lr) * K + lc;

    for (int k0 = 0; k0 < K; k0 += 32) {
        __syncthreads();
        gload16(Ag + k0,                  &As[w * 16][0]);
        gload16(Ag + k0 + (size_t)64 * K, &As[64 + w * 16][0]);
        gload16(Bg + k0,                  &Bs[w * 16][0]);
        gload16(Bg + k0 + (size_t)64 * K, &Bs[64 + w * 16][0]);
        __syncthreads();
        short8 a[4], bf[4];
#pragma unroll
        for (int m = 0; m < 4; ++m) a[m] = *(const short8*)&As[wr * 64 + m * 16 + lo][hi * 8];
#pragma unroll
        for (int n = 0; n < 4; ++n) bf[n] = *(const short8*)&Bs[wc * 64 + n * 16 + lo][hi * 8];
#pragma unroll
        for (int m = 0; m < 4; ++m)
#pragma unroll
            for (int n = 0; n < 4; ++n)
                acc[m][n] = __builtin_amdgcn_mfma_f32_16x16x32_bf16(a[m], bf[n], acc[m][n], 0, 0, 0);
    }

#pragma unroll
    for (int m = 0; m < 4; ++m)
#pragma unroll
        for (int n = 0; n < 4; ++n) {
            int col  = n0 + wc * 64 + n * 16 + lo;
            int row0 = m0 + wr * 64 + m * 16 + hi * 4;
            float bv = bias[col];
            if (col < D_MODEL) {                    // Q (pre-scaled)
#pragma unroll
                for (int r = 0; r < 4; ++r)
                    qw[(size_t)(row0 + r) * D_MODEL + col] = fb((acc[m][n][r] + bv) * SM_C);
            } else if (col < 2 * D_MODEL) {         // K -> swizzled image
                int kc2 = col - D_MODEL;
                int hh = kc2 >> 6, dh = kc2 & 63;
#pragma unroll
                for (int r = 0; r < 4; ++r) {
                    int row = row0 + r;
                    int bb = row >> 12, s = row & 4095;
                    int kb = s >> 6, kr = s & 63;
                    size_t base = (((size_t)bb * NHEAD + hh) * 64 + kb) * 4096;
                    kblk[base + kr * 64 + (((dh >> 3) ^ (kr & 7)) * 8) + (dh & 7)] =
                        fb(acc[m][n][r] + bv);
                }
            } else {                                // V -> swizzled image (4 keys contig)
                int vcol = col - 2 * D_MODEL;
                int hh = vcol >> 6, dh = vcol & 63;
                int bb = row0 >> 12, s = row0 & 4095;
                int kb = s >> 6, kr = s & 63;
                size_t base = (((size_t)bb * NHEAD + hh) * 64 + kb) * 4096;
                uint2 u = {pk2(acc[m][n][0] + bv, acc[m][n][1] + bv),
                           pk2(acc[m][n][2] + bv, acc[m][n][3] + bv)};
                *(uint2*)&vblk[base + dh * 64 + (((kr >> 3) ^ (dh & 7)) * 8) + (kr & 7)] = u;
            }
        }
}

// ---------------------------------------------------------------------------
__global__ __launch_bounds__(256) void gemm_out128(const short* __restrict__ A,
                                                   const short* __restrict__ Bt,
                                                   const float* __restrict__ bias,
                                                   float* __restrict__ C) {
    const int K = D_MODEL, N = D_MODEL;
    __shared__ short As[128][32];
    __shared__ short Bs[128][32];
    const int tid = threadIdx.x, lane = tid & 63, w = tid >> 6;
    const int wr = w >> 1, wc = w & 1;
    const int lo = lane & 15, hi = lane >> 4;
    const int m0 = blockIdx.y * 128, n0 = blockIdx.x * 128;
    const int lr = lane >> 2, lc = (lane & 3) * 8;

    floatx4 acc[4][4] = {};
    const short* Ag = A  + (size_t)(m0 + w * 16 + lr) * K + lc;
    const short* Bg = Bt + (size_t)(n0 + w * 16 + lr) * K + lc;

    for (int k0 = 0; k0 < K; k0 += 32) {
        __syncthreads();
        gload16(Ag + k0,                  &As[w * 16][0]);
        gload16(Ag + k0 + (size_t)64 * K, &As[64 + w * 16][0]);
        gload16(Bg + k0,                  &Bs[w * 16][0]);
        gload16(Bg + k0 + (size_t)64 * K, &Bs[64 + w * 16][0]);
        __syncthreads();
        short8 a[4], bf[4];
#pragma unroll
        for (int m = 0; m < 4; ++m) a[m] = *(const short8*)&As[wr * 64 + m * 16 + lo][hi * 8];
#pragma unroll
        for (int n = 0; n < 4; ++n) bf[n] = *(const short8*)&Bs[wc * 64 + n * 16 + lo][hi * 8];
#pragma unroll
        for (int m = 0; m < 4; ++m)
#pragma unroll
            for (int n = 0; n < 4; ++n)
                acc[m][n] = __builtin_amdgcn_mfma_f32_16x16x32_bf16(a[m], bf[n], acc[m][n], 0, 0, 0);
    }

#pragma unroll
    for (int m = 0; m < 4; ++m)
#pragma unroll
        for (int n = 0; n < 4; ++n) {
            int col  = n0 + wc * 64 + n * 16 + lo;
            int row0 = m0 + wr * 64 + m * 16 + hi * 4;
            float bv = bias[col];
#pragma unroll
            for (int r = 0; r < 4; ++r)
                C[(size_t)(row0 + r) * N + col] = acc[m][n][r] + bv;
        }
}

// ---------------------------------------------------------------------------
// Flash attention (causal). Pair A (w0,w1) owns tile 63-i; pair B (w2,w3)
// owns tile i then tile 63-i's tail. K/V staged by global_load_lds from
// pre-swizzled images (zero VALU staging). 33 uniform iters; 768 blocks.
// ---------------------------------------------------------------------------
__global__ __launch_bounds__(256, 3) void attn_k(const short* __restrict__ qw,
                                                 const short* __restrict__ kblk,
                                                 const short* __restrict__ vblk,
                                                 short* __restrict__ y) {
    const int L = blockIdx.x;
    const int xcd = L & 7, slot = L >> 3;
    const int ghead = slot >> 5, ip = slot & 31;
    const int g = ghead * 8 + xcd;
    const int b = g / NHEAD, h = g % NHEAD;

    const int tid = threadIdx.x, lane = tid & 63, w = tid >> 6;
    const int q32 = lane & 31, hh = lane >> 5;
    const int pairB = w >> 1;
    const int wp = w & 1;                // wave-in-pair
    const int wrow = wp * 32;

    __shared__ alignas(16) short KVs[2][2][64 * 64];  // [pair][K,V] images
    __shared__ float Lcmb[128];

    const short* qbase = qw + (size_t)b * SEQ * D_MODEL;
    const short* kimg = kblk + (((size_t)b * NHEAD + h) * 64) * 4096;
    const short* vimg = vblk + (((size_t)b * NHEAD + h) * 64) * 4096;

    short* Kb = KVs[pairB][0];
    short* Vb = KVs[pairB][1];

    // staging: wave-in-pair wp covers image half [wp*2048, wp*2048+2048) shorts
    const short* kSrc = kimg + wp * 2048 + lane * 8;
    const short* vSrc = vimg + wp * 2048 + lane * 8;
    short* kDst = Kb + wp * 2048;
    short* vDst = Vb + wp * 2048;

    const int qt_hi = 63 - ip, qt_lo = ip;
    int tq0 = (pairB ? qt_lo : qt_hi) * 64;

    short8 qf[4];
    {
        const short* qr = qbase + (size_t)(tq0 + wrow + q32) * D_MODEL + h * 64 + hh * 8;
        qf[0] = *(const short8*)(qr);
        qf[1] = *(const short8*)(qr + 16);
        qf[2] = *(const short8*)(qr + 32);
        qf[3] = *(const short8*)(qr + 48);
    }

    floatx16 O0 = {}, O1 = {};
    float lsum = 0.0f;

    auto store_out = [&](float ltot) {
        float inv = 1.0f / ltot;
#pragma unroll
        for (int r = 0; r < 16; ++r) {
            int qrow = (r & 3) + 8 * (r >> 2) + 4 * hh;
            float iv = __shfl(inv, qrow, 64);
            short* d = y + ((size_t)b * SEQ + tq0 + wrow + qrow) * D_MODEL + h * 64;
            d[q32]      = fb(O0[r] * iv);
            d[32 + q32] = fb(O1[r] * iv);
        }
    };

    for (int j = 0; j <= 32; ++j) {
        // my block this iteration (wave-uniform scalar)
        int myblk;
        if (!pairB) myblk = j;
        else        myblk = (j <= ip) ? j : (j <= 31 ? 32 + (j - ip) : -1);

        __syncthreads();
        if (myblk >= 0) {
            const short* ks = kSrc + (size_t)myblk * 4096;
            const short* vs = vSrc + (size_t)myblk * 4096;
#pragma unroll
            for (int c = 0; c < 4; ++c) {
                gload16(ks + c * 512, kDst + c * 512);
                gload16(vs + c * 512, vDst + c * 512);
            }
        }
        __syncthreads();   // drains vmcnt -> LDS images ready

        // pair B: finalize T_lo and retarget to T_hi tail
        if (pairB && j == ip + 1) {
            float ltot = lsum + __shfl_xor(lsum, 32, 64);
            store_out(ltot);
#pragma unroll
            for (int r = 0; r < 16; ++r) { O0[r] = 0.0f; O1[r] = 0.0f; }
            lsum = 0.0f;
            tq0 = qt_hi * 64;
            const short* qr = qbase + (size_t)(tq0 + wrow + q32) * D_MODEL + h * 64 + hh * 8;
            qf[0] = *(const short8*)(qr);
            qf[1] = *(const short8*)(qr + 16);
            qf[2] = *(const short8*)(qr + 32);
            qf[3] = *(const short8*)(qr + 48);
        }

        if (myblk >= 0) {
            const int myqt = (pairB && j <= ip) ? qt_lo : qt_hi;
            const bool diag = (myblk == myqt);

#pragma unroll
            for (int kb2 = 0; kb2 < 2; ++kb2) {
                floatx16 S = {};
                __builtin_amdgcn_s_setprio(1);
#pragma unroll
                for (int kc = 0; kc < 4; ++kc) {
                    short8 kf = *(const short8*)&Kb[(kb2 * 32 + q32) * 64 + ((kc * 2 + hh) ^ (q32 & 7)) * 8];
                    S = __builtin_amdgcn_mfma_f32_32x32x16_bf16(kf, qf[kc], S, 0, 0, 0);
                }
                __builtin_amdgcn_s_setprio(0);

                if (diag) {
                    int qg = tq0 + wrow + q32;
                    int kb_base = myblk * 64 + kb2 * 32 + 4 * hh;
#pragma unroll
                    for (int r = 0; r < 16; ++r) {
                        int kgl = kb_base + (r & 3) + 8 * (r >> 2);
                        if (kgl > qg) S[r] = -1e30f;
                    }
                }

                unsigned wA[4], wB[4];
#pragma unroll
                for (int g4 = 0; g4 < 4; ++g4) {
                    float p0 = EXP2(S[4 * g4 + 0]), p1 = EXP2(S[4 * g4 + 1]);
                    float p2 = EXP2(S[4 * g4 + 2]), p3 = EXP2(S[4 * g4 + 3]);
                    lsum += (p0 + p1) + (p2 + p3);
                    wA[g4] = pk2(p0, p1);
                    wB[g4] = pk2(p2, p3);
                }
#pragma unroll
                for (int c16 = 0; c16 < 2; ++c16) {
                    unsigned xa = wA[2 * c16], ya = wA[2 * c16 + 1];
                    unsigned xb = wB[2 * c16], yb = wB[2 * c16 + 1];
                    asm("v_permlane32_swap_b32 %0, %1" : "+v"(xa), "+v"(ya));
                    asm("v_permlane32_swap_b32 %0, %1" : "+v"(xb), "+v"(yb));
                    union { unsigned u[4]; short8 s; } pa;
                    pa.u[0] = xa; pa.u[1] = xb; pa.u[2] = ya; pa.u[3] = yb;
                    const int kc = kb2 * 2 + c16;
                    short8 vf0 = *(const short8*)&Vb[q32 * 64 + ((kc * 2 + hh) ^ (q32 & 7)) * 8];
                    short8 vf1 = *(const short8*)&Vb[(32 + q32) * 64 + ((kc * 2 + hh) ^ (q32 & 7)) * 8];
                    __builtin_amdgcn_s_setprio(1);
                    O0 = __builtin_amdgcn_mfma_f32_32x32x16_bf16(pa.s, vf0, O0, 0, 0, 0);
                    O1 = __builtin_amdgcn_mfma_f32_32x32x16_bf16(pa.s, vf1, O1, 0, 0, 0);
                    __builtin_amdgcn_s_setprio(0);
                }
            }
        }
    }

    // combine: B writes fp32 partials over its own (now-dead) buffers; A adds.
    if (pairB) {
        float* cO = (float*)&KVs[1][0][0];
        const int lane2 = wp * 64 + lane;
#pragma unroll
        for (int r = 0; r < 16; ++r) {
            cO[r * 128 + lane2]        = O0[r];
            cO[(16 + r) * 128 + lane2] = O1[r];
        }
        Lcmb[lane2] = lsum;
    }
    __syncthreads();
    if (!pairB) {
        const float* cO = (const float*)&KVs[1][0][0];
        const int lane2 = wp * 64 + lane;
#pragma unroll
        for (int r = 0; r < 16; ++r) {
            O0[r] += cO[r * 128 + lane2];
            O1[r] += cO[(16 + r) * 128 + lane2];
        }
        lsum += Lcmb[lane2];
        float ltot = lsum + __shfl_xor(lsum, 32, 64);
        store_out(ltot);
    }
}

extern "C" void kernel_launch(void* const* d_in, const int* in_sizes, int n_in,
                              void* d_out, int out_size, void* d_ws, size_t ws_size,
                              hipStream_t stream) {
    (void)in_sizes; (void)n_in; (void)out_size; (void)ws_size;
    const float* x     = (const float*)d_in[0];
    const float* W_in  = (const float*)d_in[1];
    const float* b_in  = (const float*)d_in[2];
    const float* W_out = (const float*)d_in[3];
    const float* b_out = (const float*)d_in[4];
    float* out = (float*)d_out;

    const int M = NB * SEQ;  // 8192
    char* p = (char*)d_ws;
    short* xbf   = (short*)p; p += (size_t)M * D_MODEL * 2;
    short* wtin  = (short*)p; p += (size_t)3 * D_MODEL * D_MODEL * 2;
    short* wtout = (short*)p; p += (size_t)D_MODEL * D_MODEL * 2;
    short* qw    = (short*)p; p += (size_t)M * D_MODEL * 2;
    short* kblk  = (short*)p; p += (size_t)NB * NHEAD * 64 * 4096 * 2;
    short* vblk  = (short*)p; p += (size_t)NB * NHEAD * 64 * 4096 * 2;
    short* yw    = (short*)p;

    convert_bf16<<<dim3((unsigned)((size_t)M * D_MODEL / 8 / 256)), 256, 0, stream>>>(
        x, xbf, (size_t)M * D_MODEL);
    transpose_bf16<<<dim3(3 * D_MODEL / 32, D_MODEL / 32), dim3(32, 8), 0, stream>>>(
        W_in, wtin, D_MODEL, 3 * D_MODEL);
    transpose_bf16<<<dim3(D_MODEL / 32, D_MODEL / 32), dim3(32, 8), 0, stream>>>(
        W_out, wtout, D_MODEL, D_MODEL);
    gemm_qkv128<<<dim3(3 * D_MODEL / 128, M / 128), 256, 0, stream>>>(
        xbf, wtin, b_in, qw, kblk, vblk);
    attn_k<<<dim3(NB * NHEAD * (SEQ / 128)), 256, 0, stream>>>(qw, kblk, vblk, yw);
    gemm_out128<<<dim3(D_MODEL / 128, M / 128), 256, 0, stream>>>(yw, wtout, b_out, out);
}